// Round 6
// baseline (835.650 us; speedup 1.0000x reference)
//
#include <hip/hip_runtime.h>
#include <stdint.h>

typedef short short8 __attribute__((ext_vector_type(8)));
typedef float floatx16 __attribute__((ext_vector_type(16)));

#define NPTS 16384
#define TILE_M 64
#define THREADS 1024
#define PA 2   // A-fragment (LDS) prefetch depth
#define PB 4   // B-fragment (global/L2) prefetch depth

// f32 -> bf16 RNE via hardware cvt (v_cvt_pk_bf16_f32 on gfx950); bit-identical
// to the old add-round-shift sequence but 1 instr instead of ~5.
__device__ inline unsigned short f2bf(float f) {
  __bf16 h = (__bf16)f;
  return __builtin_bit_cast(unsigned short, h);
}
__device__ inline float bf2f(unsigned short h) {
  union { unsigned u; float f; } v; v.u = ((unsigned)h) << 16;
  return v.f;
}

// Persistent NODE integrator: 1024 threads (16 waves) per WG, TILE_M=64,
// 256 WGs -> 16 waves/CU = 4 waves/SIMD. waves_per_eu(4,4) pins the register
// allocator at the 128-VGPR budget (round-5 build chose 64 and spilled:
// WRITE_SIZE 0.19->15.5 MB scratch traffic).
// Each wave owns ONE 32-col output block per GEMM (acc=32 regs, 1 B-stream).
__global__
__attribute__((amdgpu_flat_work_group_size(THREADS, THREADS),
               amdgpu_waves_per_eu(4, 4)))
void node_kernel(
    const float* __restrict__ x, float* __restrict__ outp,
    const unsigned short* __restrict__ wbf, const float* __restrict__ sfall,
    const float* __restrict__ w1a, const float* __restrict__ b1a,
    const float* __restrict__ b2a, const float* __restrict__ b3a,
    const float* __restrict__ w4a, const float* __restrict__ b4a,
    const float* __restrict__ w1b, const float* __restrict__ b1b,
    const float* __restrict__ b2b, const float* __restrict__ b3b,
    const float* __restrict__ w4b, const float* __restrict__ b4b)
{
  // act: 64 x 512 bf16, row pitch 520 u16 (1040 B = 65*16B -> afrag b128
  // reads land row r on bank-quad r%8 => conflict-free). 66560 B.
  __shared__ unsigned short act[TILE_M][520];
  __shared__ float pcur4[TILE_M][4];  // integrated position (float4 padded)
  __shared__ float pev4[TILE_M][4];   // stage evaluation point
  __shared__ float kac4[TILE_M][4];   // RK4 accumulator
  __shared__ float w4s[3][512];       // staged W4 (fp32), 6144 B

  const int tid = threadIdx.x;
  const int wg = blockIdx.x;
  const int m0 = wg * TILE_M;
  const int batch = wg >> 6;          // 64 WGs per batch (4096/64)
  const int lane = tid & 63;
  const int wid = tid >> 6;           // 0..15: owns cols [wid*32, wid*32+32)

  // ---- init state from x ----
  if (tid < TILE_M * 3) {
    int m = tid / 3, c = tid % 3;
    float v = x[m0 * 3 + tid];
    pcur4[m][c] = v;
    pev4[m][c] = v;
  }
  __syncthreads();

  // A-frag (32x32x16): lane holds act[rb*32+(lane&31)][kt*16 + (lane>>5)*8 ..+8]
  // B-frag: fragment-major wf[((kt*16 + nt)*64 + lane)*8], nt = wid
  const int aBase = (lane & 31) * 1040 + (lane >> 5) * 16;   // bytes
  const char* actB = (const char*)&act[0][0];
  const int bcol = wid * 64 + lane;                          // short8 index

  // phase-1 column owned by this thread (2 threads per column, split rows)
  const int p1col = tid & 511;
  const int p1r0 = (tid >> 9) * 32;

  const float dt = 0.05f;

  #pragma unroll 1
  for (int f = 0; f < 2; ++f) {
    const float* w1 = f ? w1b : w1a;
    const float* b1v = f ? b1b : b1a;
    const float* b2v = f ? b2b : b2a;
    const float* b3v = f ? b3b : b3a;
    const float* w4 = f ? w4b : w4a;
    const float* b4v = f ? b4b : b4a;
    const short8* w2p = (const short8*)(wbf + (size_t)(f * 2 + 0) * 262144) + bcol;
    const short8* w3p = (const short8*)(wbf + (size_t)(f * 2 + 1) * 262144) + bcol;

    // hoisted per-block-f phase-1 / phase-4 constants
    const float ww0 = w1[p1col * 3 + 0], ww1 = w1[p1col * 3 + 1], ww2 = w1[p1col * 3 + 2];
    const float bb = b1v[p1col];
    const float ss = sfall[f * 2048 + batch * 512 + p1col];
    const float b40 = b4v[0], b41 = b4v[1], b42 = b4v[2];

    // stage W4 (3x512 fp32) into LDS once per f-block
    for (int i = tid; i < 1536; i += THREADS) ((float*)w4s)[i] = w4[i];
    __syncthreads();

    #pragma unroll 1
    for (int st = 0; st < 4; ++st) {
      #pragma unroll 1
      for (int stage = 0; stage < 4; ++stage) {
        // issue s=0 B prefetch before phase 1: restart the L2 weight stream
        // while the VALU phase runs (no dependency on act)
        short8 bq[PB];
        #pragma unroll
        for (int i = 0; i < PB - 1; ++i) bq[i] = w2p[i * 1024];

        // ---- phase 1: act = relu(pev@W1.T + b1) * sf ----
        // rows p1r0..p1r0+31, column p1col; pev read is a b128 broadcast
        #pragma unroll 4
        for (int mi = 0; mi < 32; ++mi) {
          int m = p1r0 + mi;
          const float4 pv = *(const float4*)&pev4[m][0];
          float v = fmaf(pv.x, ww0, fmaf(pv.y, ww1, fmaf(pv.z, ww2, bb)));
          v = fmaxf(v, 0.f) * ss;
          act[m][p1col] = f2bf(v);
        }
        __syncthreads();

        // ---- phases 2+3: two residual GEMMs, h = relu(h@W.T + b) + h ----
        #pragma unroll 1
        for (int s = 0; s < 2; ++s) {
          const float* bias = s ? b3v : b2v;
          const short8* bp = s ? w3p : w2p;
          floatx16 acc0{}, acc1{};
          short8 aq0[PA], aq1[PA];
          #pragma unroll
          for (int i = 0; i < PA - 1; ++i) {
            aq0[i] = *(const short8*)(actB + aBase + i * 32);
            aq1[i] = *(const short8*)(actB + aBase + 33280 + i * 32);
          }

          #pragma unroll
          for (int kt = 0; kt < 32; ++kt) {
            int la = kt + PA - 1;
            if (la < 32) {
              aq0[la % PA] = *(const short8*)(actB + aBase + la * 32);
              aq1[la % PA] = *(const short8*)(actB + aBase + 33280 + la * 32);
            }
            int lb = kt + PB - 1;
            if (lb < 32) bq[lb % PB] = bp[lb * 1024];
            acc0 = __builtin_amdgcn_mfma_f32_32x32x16_bf16(aq0[kt % PA], bq[kt % PB], acc0, 0, 0, 0);
            acc1 = __builtin_amdgcn_mfma_f32_32x32x16_bf16(aq1[kt % PA], bq[kt % PB], acc1, 0, 0, 0);
          }

          // restart the NEXT GEMM's B-stream (W3) now: its L2 latency hides
          // under the epilogue + barriers below (no dependency on act)
          if (s == 0) {
            #pragma unroll
            for (int i = 0; i < PB - 1; ++i) bq[i] = w3p[i * 1024];
          }

          __syncthreads();   // all waves done reading act before epilogue writes
          // epilogue: C/D layout col=lane&31, row=(reg&3)+8*(reg>>2)+4*(lane>>5)
          // 4-reg groups: batch 8 independent LDS reads, then compute+write.
          // Small live range (8 floats) -> no spill at the 128-VGPR budget.
          {
            int ncol = wid * 32 + (lane & 31);
            float bs = bias[ncol];
            int rbase = 4 * (lane >> 5);
            #pragma unroll
            for (int g = 0; g < 4; ++g) {
              float r0[4], r1[4];
              #pragma unroll
              for (int i = 0; i < 4; ++i) {
                int row = i + 8 * g + rbase;
                r0[i] = bf2f(act[row][ncol]);
                r1[i] = bf2f(act[32 + row][ncol]);
              }
              #pragma unroll
              for (int i = 0; i < 4; ++i) {
                int row = i + 8 * g + rbase;
                float v = fmaxf(acc0[g * 4 + i] + bs, 0.f) + r0[i];
                act[row][ncol] = f2bf(v);
                v = fmaxf(acc1[g * 4 + i] + bs, 0.f) + r1[i];
                act[32 + row][ncol] = f2bf(v);
              }
            }
          }
          __syncthreads();
        }

        // ---- phase 4: flow = tanh(act@W4.T + b4), then RK4 stage update ----
        // 16-lane groups per point; 4 chunks of short8 (b128 act reads);
        // W4 from LDS fp32 via float4 (broadcast across groups sharing jj)
        {
          int m = tid >> 4, jj = tid & 15;
          const unsigned short* arow = &act[m][0];
          float s0 = 0.f, s1 = 0.f, s2 = 0.f;
          #pragma unroll
          for (int c = 0; c < 4; ++c) {
            int k0 = (c * 16 + jj) * 8;
            short8 av = *(const short8*)(arow + k0);
            #pragma unroll
            for (int half = 0; half < 2; ++half) {
              float4 wv0 = *(const float4*)&w4s[0][k0 + half * 4];
              float4 wv1 = *(const float4*)&w4s[1][k0 + half * 4];
              float4 wv2 = *(const float4*)&w4s[2][k0 + half * 4];
              #pragma unroll
              for (int e = 0; e < 4; ++e) {
                float a = bf2f((unsigned short)av[half * 4 + e]);
                s0 = fmaf(a, ((const float*)&wv0)[e], s0);
                s1 = fmaf(a, ((const float*)&wv1)[e], s1);
                s2 = fmaf(a, ((const float*)&wv2)[e], s2);
              }
            }
          }
          s0 += __shfl_xor(s0, 1); s1 += __shfl_xor(s1, 1); s2 += __shfl_xor(s2, 1);
          s0 += __shfl_xor(s0, 2); s1 += __shfl_xor(s1, 2); s2 += __shfl_xor(s2, 2);
          s0 += __shfl_xor(s0, 4); s1 += __shfl_xor(s1, 4); s2 += __shfl_xor(s2, 4);
          s0 += __shfl_xor(s0, 8); s1 += __shfl_xor(s1, 8); s2 += __shfl_xor(s2, 8);
          if (jj < 3) {
            float sv = (jj == 0) ? s0 : ((jj == 1) ? s1 : s2);
            float bv = (jj == 0) ? b40 : ((jj == 1) ? b41 : b42);
            float fl = tanhf(sv + bv);
            float pc = pcur4[m][jj];
            if (stage == 0) {
              kac4[m][jj] = fl;
              pev4[m][jj] = fmaf(0.5f * dt, fl, pc);
            } else if (stage == 1) {
              kac4[m][jj] += 2.f * fl;
              pev4[m][jj] = fmaf(0.5f * dt, fl, pc);
            } else if (stage == 2) {
              kac4[m][jj] += 2.f * fl;
              pev4[m][jj] = fmaf(dt, fl, pc);
            } else {
              float np = fmaf(dt / 6.f, kac4[m][jj] + fl, pc);
              pcur4[m][jj] = np;
              pev4[m][jj] = np;
            }
          }
        }
        __syncthreads();
      }
    }
  }

  // ---- write final positions ----
  if (tid < TILE_M * 3) outp[m0 * 3 + tid] = pcur4[tid / 3][tid % 3];
}

// ---- setup: shuffle W (512x512 fp32 row-major, W[n][k]) into fragment-major
// bf16: dst[((kt*16 + nt)*64 + lane)*8 + j] = W[nt*32+(lane&31)][kt*16+(lane>>5)*8+j]
__global__ void setup_shuffle(const float* s0, const float* s1, const float* s2,
                              const float* s3, unsigned short* dst) {
  int idx = blockIdx.x * blockDim.x + threadIdx.x;   // 4 * 32768
  int w = idx >> 15;
  int r = idx & 32767;            // (kt*16+nt)*64 + lane
  int lane = r & 63;
  int tile = r >> 6;
  int nt = tile & 15, kt = tile >> 4;
  const float* W = (w == 0) ? s0 : (w == 1) ? s1 : (w == 2) ? s2 : s3;
  int n = nt * 32 + (lane & 31);
  int k0 = kt * 16 + (lane >> 5) * 8;
  const float* src = W + n * 512 + k0;
  unsigned short* d = dst + ((size_t)w << 18) + (size_t)r * 8;
  #pragma unroll
  for (int j = 0; j < 8; ++j) d[j] = f2bf(src[j]);
}

__global__ void setup_sf(const float* code, const float* cw1, const float* cb1,
                         const float* cw2, const float* cb2, float* sfout) {
  int f = blockIdx.x >> 2, b = blockIdx.x & 3;
  const float* cw = f ? cw2 : cw1;
  const float* cb = f ? cb2 : cb1;
  int j = threadIdx.x;
  const float* c = code + b * 512;
  float s = cb[j];
  for (int k = 0; k < 512; ++k) s = fmaf(c[k], cw[j * 512 + k], s);
  sfout[f * 2048 + b * 512 + j] = tanhf(s);
}

extern "C" void kernel_launch(void* const* d_in, const int* in_sizes, int n_in,
                              void* d_out, int out_size, void* d_ws, size_t ws_size,
                              hipStream_t stream) {
  const float* code = (const float*)d_in[0];
  const float* x    = (const float*)d_in[1];
  char* ws = (char*)d_ws;
  float* sf = (float*)ws;                               // 2*2048 fp32 = 16 KB
  unsigned short* wbf = (unsigned short*)(ws + 16384);  // 4 * 262144 u16 = 2 MB

  setup_shuffle<<<512, 256, 0, stream>>>((const float*)d_in[4], (const float*)d_in[6],
                                         (const float*)d_in[14], (const float*)d_in[16], wbf);
  setup_sf<<<8, 512, 0, stream>>>(code, (const float*)d_in[10], (const float*)d_in[11],
                                  (const float*)d_in[20], (const float*)d_in[21], sf);

  node_kernel<<<NPTS / TILE_M, THREADS, 0, stream>>>(x, (float*)d_out, wbf, sf,
      (const float*)d_in[2], (const float*)d_in[3], (const float*)d_in[5],
      (const float*)d_in[7], (const float*)d_in[8], (const float*)d_in[9],
      (const float*)d_in[12], (const float*)d_in[13], (const float*)d_in[15],
      (const float*)d_in[17], (const float*)d_in[18], (const float*)d_in[19]);
}